// Round 6
// baseline (282.394 us; speedup 1.0000x reference)
//
#include <hip/hip_runtime.h>
#include <math.h>

#define NN   32768
#define EE   524288
#define ETOT (EE + NN)
#define BB   32
#define NPG  1024
#define EPG  16384
#define RPG  17408          // CSR entries per graph = EPG + NPG (self-loops)
#define KK   512
#define INC  128
#define HID  64
#define NH   4
#define CC   256
#define SLOPE 0.2f

// ---------------- GEMM1 + al epilogue ----------------
// 128x128 tile, 8x8 micro (VALU-bound: 128 FMA-cyc vs ~24 LDS-cyc per k-iter).
// 66 KB LDS -> 2 blocks/CU; grid 512 = all-resident. XCD swizzle: rows
// [4096*xcd, +4095] are produced on XCD xcd (consumed there by agg).
// Per-element k order ascending 0..127 -> h/al bit-identical to R5.
__global__ __launch_bounds__(256) void gemm1_al_kernel(const float* __restrict__ x,
                                                       const float* __restrict__ W,
                                                       const float* __restrict__ a_src,
                                                       const float* __restrict__ a_dst,
                                                       float* __restrict__ h,
                                                       float* __restrict__ al_s,
                                                       float* __restrict__ al_d) {
  __shared__ float As[128][65];
  __shared__ float Bs[64][128];
  const int lid = blockIdx.x;            // 512 blocks: 8 xcd x 32 ntile x 2 ctile
  const int xcd = lid & 7;
  const int t8  = lid >> 3;              // 0..63
  const int n0 = (xcd * 32 + (t8 & 31)) * 128;
  const int c0 = (t8 >> 5) * 128;
  const int tid = threadIdx.x;
  const int rowg = tid >> 4;             // 0..15 (8 rows each)
  const int colg = tid & 15;             // 0..15 (8 cols each)
  const int lr = tid >> 4, lq = tid & 15;
  float acc[8][8] = {};
  for (int kc = 0; kc < 2; ++kc) {
    const int k0 = kc * 64;
#pragma unroll
    for (int p = 0; p < 8; ++p) {        // A: 128 rows x 64 k
      int row = p * 16 + lr;
      float4 v = *(const float4*)(x + (size_t)(n0 + row) * INC + k0 + lq * 4);
      As[row][lq * 4 + 0] = v.x; As[row][lq * 4 + 1] = v.y;
      As[row][lq * 4 + 2] = v.z; As[row][lq * 4 + 3] = v.w;
    }
#pragma unroll
    for (int p = 0; p < 8; ++p) {        // B: 64 k x 128 c
      int krow = (p & 3) * 16 + lr;
      int coff = (p >> 2) * 64 + lq * 4;
      *(float4*)(&Bs[krow][coff]) =
          *(const float4*)(W + (size_t)(k0 + krow) * CC + c0 + coff);
    }
    __syncthreads();
#pragma unroll
    for (int k = 0; k < 64; ++k) {
      float a[8];
#pragma unroll
      for (int i = 0; i < 8; ++i) a[i] = As[rowg * 8 + i][k];
      float4 b0 = *(const float4*)(&Bs[k][colg * 8]);
      float4 b1 = *(const float4*)(&Bs[k][colg * 8 + 4]);
#pragma unroll
      for (int i = 0; i < 8; ++i) {
        acc[i][0] += a[i] * b0.x; acc[i][1] += a[i] * b0.y;
        acc[i][2] += a[i] * b0.z; acc[i][3] += a[i] * b0.w;
        acc[i][4] += a[i] * b1.x; acc[i][5] += a[i] * b1.y;
        acc[i][6] += a[i] * b1.z; acc[i][7] += a[i] * b1.w;
      }
    }
    __syncthreads();
  }
  // al epilogue: this thread's 8 cols lie in one head (head = c0/64 + colg>>3)
  const int head = (c0 >> 6) + (colg >> 3);
  const float4 as0 = *(const float4*)(a_src + c0 + colg * 8);
  const float4 as1 = *(const float4*)(a_src + c0 + colg * 8 + 4);
  const float4 ad0 = *(const float4*)(a_dst + c0 + colg * 8);
  const float4 ad1 = *(const float4*)(a_dst + c0 + colg * 8 + 4);
#pragma unroll
  for (int i = 0; i < 8; ++i) {
    float* hp = h + (size_t)(n0 + rowg * 8 + i) * CC + c0 + colg * 8;
    *(float4*)(hp)     = make_float4(acc[i][0], acc[i][1], acc[i][2], acc[i][3]);
    *(float4*)(hp + 4) = make_float4(acc[i][4], acc[i][5], acc[i][6], acc[i][7]);
    float ps = 0.f, pd = 0.f;
    ps += acc[i][0] * as0.x; ps += acc[i][1] * as0.y; ps += acc[i][2] * as0.z; ps += acc[i][3] * as0.w;
    ps += acc[i][4] * as1.x; ps += acc[i][5] * as1.y; ps += acc[i][6] * as1.z; ps += acc[i][7] * as1.w;
    pd += acc[i][0] * ad0.x; pd += acc[i][1] * ad0.y; pd += acc[i][2] * ad0.z; pd += acc[i][3] * ad0.w;
    pd += acc[i][4] * ad1.x; pd += acc[i][5] * ad1.y; pd += acc[i][6] * ad1.z; pd += acc[i][7] * ad1.w;
#pragma unroll
    for (int off = 4; off > 0; off >>= 1) {   // reduce the 8 lanes of one head
      ps += __shfl_down(ps, off, 8);
      pd += __shfl_down(pd, off, 8);
    }
    if ((colg & 7) == 0) {
      al_s[(n0 + rowg * 8 + i) * NH + head] = ps;
      al_d[(n0 + rowg * 8 + i) * NH + head] = pd;
    }
  }
}

// ---------------- CSR build: edge-parallel, global atomics ----------------
// XCD swizzle: edges of graph g processed on XCD g>>2.
__global__ void count_kernel(const int* __restrict__ ei, int* __restrict__ cnt) {
  const int lid = blockIdx.x;                       // 512 blocks x 1024 edges
  const int e = (((lid & 7) * 64 + (lid >> 3)) * 1024) + threadIdx.x * 4;
  const int4 d4 = *(const int4*)(ei + EE + e);
  atomicAdd(&cnt[d4.x], 1);
  atomicAdd(&cnt[d4.y], 1);
  atomicAdd(&cnt[d4.z], 1);
  atomicAdd(&cnt[d4.w], 1);
}

// per-graph LDS scan; also initializes the scatter cursor (cnt2 = row_ptr).
__global__ __launch_bounds__(1024) void scan_g_kernel(const int* __restrict__ cnt,
                                                      int* __restrict__ row_ptr,
                                                      int* __restrict__ cnt2) {
  __shared__ int sums[NPG];
  const int lid = blockIdx.x, t = threadIdx.x;
  const int b = (lid & 7) * 4 + (lid >> 3);
  const int c = cnt[b * NPG + t] + 1;               // + self-loop
  sums[t] = c;
  __syncthreads();
  for (int off = 1; off < NPG; off <<= 1) {
    int v = (t >= off) ? sums[t - off] : 0;
    __syncthreads();
    sums[t] += v;
    __syncthreads();
  }
  const int pos = b * RPG + sums[t] - c;
  row_ptr[b * NPG + t] = pos;
  cnt2[b * NPG + t] = pos;
  if (lid == 0 && t == 0) row_ptr[NN] = ETOT;
}

__global__ void scatter_w_kernel(const int* __restrict__ ei,
                                 int* __restrict__ cnt2,
                                 const float* __restrict__ al_s,
                                 const float* __restrict__ al_d,
                                 int* __restrict__ col, float* __restrict__ w4) {
  const int lid = blockIdx.x;                       // 544 blocks x 1024 edges
  const int ebase = (((lid & 7) * 68 + (lid >> 3)) * 1024) + threadIdx.x * 4;
#pragma unroll
  for (int u = 0; u < 4; ++u) {
    const int e = ebase + u;
    int s, d;
    if (e < EE) { s = ei[e]; d = ei[EE + e]; } else { s = e - EE; d = s; }
    int pos = atomicAdd(&cnt2[d], 1);
    col[pos] = s;
    const float4 as = *(const float4*)(al_s + s * NH);
    const float4 ad = *(const float4*)(al_d + d * NH);
    float e0 = as.x + ad.x; e0 = (e0 > 0.f) ? e0 : SLOPE * e0; float w0 = __expf(e0);
    float e1 = as.y + ad.y; e1 = (e1 > 0.f) ? e1 : SLOPE * e1; float w1 = __expf(e1);
    float e2 = as.z + ad.z; e2 = (e2 > 0.f) ? e2 : SLOPE * e2; float w2 = __expf(e2);
    float e3 = as.w + ad.w; e3 = (e3 > 0.f) ? e3 : SLOPE * e3; float w3 = __expf(e3);
    *(float4*)(w4 + (size_t)pos * 4) = make_float4(w0, w1, w2, w3);
  }
}

// ---------------- weighted aggregation (wave per dst node) ----------------
// Lane l owns channels 4l..4l+3 (head = l>>4): one dwordx4 per edge per lane.
// Edge metadata staged per-wave into LDS (wave-coherent, no barrier).
// 2-deep software pipeline on the h-row gather. XCD swizzle matches gemm1_al
// h writes and scatter_w col/w4 writes.
__global__ __launch_bounds__(256) void agg_kernel(const float* __restrict__ h,
                                                  const float* __restrict__ w4,
                                                  const int* __restrict__ row_ptr,
                                                  const int* __restrict__ col,
                                                  const float* __restrict__ b_gat,
                                                  float* __restrict__ outg) {
  __shared__ float wsh[4][256];
  __shared__ int   csh[4][64];
  const int lane = threadIdx.x & 63;
  const int wv = threadIdx.x >> 6;
  const int hq = lane >> 4;
  const int xcd = blockIdx.x & 7;
  const int jb  = blockIdx.x >> 3;
  const int n = (xcd * 1024 + jb) * 4 + wv;
  const int beg = row_ptr[n], end = row_ptr[n + 1];
  float ax = 0.f, ay = 0.f, az = 0.f, aw = 0.f, den = 0.f;
  for (int base = beg; base < end; base += 64) {
    const int rem = end - base;
    const int cnt = rem < 64 ? rem : 64;
    if (lane < cnt) {
      csh[wv][lane] = col[base + lane];
      *(float4*)(&wsh[wv][lane * 4]) = *(const float4*)(w4 + (size_t)(base + lane) * 4);
    }
    // wave-coherent LDS: all lanes of this wave wrote before any lane reads
    float4 hA = *(const float4*)(h + (size_t)csh[wv][0] * CC + lane * 4);
    float4 hB = hA;
    if (cnt > 1) hB = *(const float4*)(h + (size_t)csh[wv][1] * CC + lane * 4);
    for (int i = 0; i < cnt; ++i) {
      const float w = wsh[wv][i * 4 + hq];
      float4 cur = hA;
      hA = hB;
      if (i + 2 < cnt)
        hB = *(const float4*)(h + (size_t)csh[wv][i + 2] * CC + lane * 4);
      den += w;
      ax += w * cur.x; ay += w * cur.y; az += w * cur.z; aw += w * cur.w;
    }
  }
  const float4 bg = *(const float4*)(b_gat + lane * 4);
  float4 o = make_float4(ax / den + bg.x, ay / den + bg.y,
                         az / den + bg.z, aw / den + bg.w);
  *(float4*)(outg + (size_t)n * CC + lane * 4) = o;
}

// ---------------- GEMM2: xl[N,64] = outg[N,256] @ W_lin + b_lin ----------------
// XCD swizzle: block reads outg rows its XCD just wrote (L2-local).
__global__ __launch_bounds__(256) void gemm2_kernel(const float* __restrict__ A,
                                                    const float* __restrict__ Wl,
                                                    const float* __restrict__ bl,
                                                    float* __restrict__ xl) {
  __shared__ float As[128][65];
  __shared__ float Bs[64][64];
  const int lid = blockIdx.x;                     // 256 blocks
  const int n0 = ((lid & 7) * 32 + (lid >> 3)) * 128;
  const int tid = threadIdx.x;
  const int rowg = tid >> 3, colg = tid & 7;
  const int lr = tid >> 4, lq = tid & 15;
  float acc[4][8] = {};
  for (int kc = 0; kc < 4; ++kc) {
    const int k0 = kc * 64;
#pragma unroll
    for (int p = 0; p < 8; ++p) {
      int row = p * 16 + lr;
      float4 v = *(const float4*)(A + (size_t)(n0 + row) * CC + k0 + lq * 4);
      As[row][lq * 4 + 0] = v.x; As[row][lq * 4 + 1] = v.y;
      As[row][lq * 4 + 2] = v.z; As[row][lq * 4 + 3] = v.w;
    }
#pragma unroll
    for (int p = 0; p < 4; ++p) {
      int krow = p * 16 + lr;
      *(float4*)(&Bs[krow][lq * 4]) =
          *(const float4*)(Wl + (size_t)(k0 + krow) * HID + lq * 4);
    }
    __syncthreads();
#pragma unroll
    for (int k = 0; k < 64; ++k) {
      float4 b0 = *(const float4*)(&Bs[k][colg * 8]);
      float4 b1 = *(const float4*)(&Bs[k][colg * 8 + 4]);
#pragma unroll
      for (int i = 0; i < 4; ++i) {
        float a = As[rowg * 4 + i][k];
        acc[i][0] += a * b0.x; acc[i][1] += a * b0.y;
        acc[i][2] += a * b0.z; acc[i][3] += a * b0.w;
        acc[i][4] += a * b1.x; acc[i][5] += a * b1.y;
        acc[i][6] += a * b1.z; acc[i][7] += a * b1.w;
      }
    }
    __syncthreads();
  }
  const float4 bv0 = *(const float4*)(bl + colg * 8);
  const float4 bv1 = *(const float4*)(bl + colg * 8 + 4);
#pragma unroll
  for (int i = 0; i < 4; ++i) {
    float* xp = xl + (size_t)(n0 + rowg * 4 + i) * HID + colg * 8;
    *(float4*)(xp)     = make_float4(acc[i][0] + bv0.x, acc[i][1] + bv0.y,
                                     acc[i][2] + bv0.z, acc[i][3] + bv0.w);
    *(float4*)(xp + 4) = make_float4(acc[i][4] + bv1.x, acc[i][5] + bv1.y,
                                     acc[i][6] + bv1.z, acc[i][7] + bv1.w);
  }
}

// ---------------- fused score + top-k + xp + nmap + pool ----------------
__device__ inline unsigned long long shflx64(unsigned long long v, int m) {
  int lo = __shfl_xor((int)(unsigned)v, m, 64);
  int hi = __shfl_xor((int)(unsigned)(v >> 32), m, 64);
  return ((unsigned long long)(unsigned)hi << 32) | (unsigned)lo;
}

__global__ __launch_bounds__(1024) void topk_fused_kernel(const float* __restrict__ xl,
                                                          const float* __restrict__ p,
                                                          float* __restrict__ out_xp,
                                                          int* __restrict__ nmap,
                                                          float* __restrict__ out_batch,
                                                          float* __restrict__ out_x1) {
  __shared__ float scv[NPG];
  __shared__ unsigned long long keys[NPG];
  __shared__ int   pidx[KK];
  __shared__ float tvs[KK];
  __shared__ float ps[16][64];
  __shared__ float pm[16][64];
  const int lid = blockIdx.x, t = threadIdx.x;
  const int b = (lid & 7) * 4 + (lid >> 3);        // graph b on XCD b>>2 (xl-local)
  float pp = 0.f, dot = 0.f;
  const float* xr = xl + (size_t)(b * NPG + t) * HID;
#pragma unroll
  for (int q = 0; q < 16; ++q) {
    float4 w = *(const float4*)(p + q * 4);
    float4 v = *(const float4*)(xr + q * 4);
    pp += w.x * w.x; pp += w.y * w.y; pp += w.z * w.z; pp += w.w * w.w;
    dot += v.x * w.x; dot += v.y * w.y; dot += v.z * w.z; dot += v.w * w.w;
  }
  float sc = tanhf(dot / sqrtf(pp));
  scv[t] = sc;
  nmap[b * NPG + t] = -1;
  unsigned long long v;
  {
    unsigned u = __float_as_uint(sc);
    u = (u & 0x80000000u) ? ~u : (u | 0x80000000u);
    u = ~u;
    v = ((unsigned long long)u << 32) | (unsigned)t;
  }
  __syncthreads();
  for (int k = 2; k <= NPG; k <<= 1) {
    for (int j = k >> 1; j > 0; j >>= 1) {
      unsigned long long pv;
      if (j >= 64) {
        keys[t] = v;
        __syncthreads();
        pv = keys[t ^ j];
        __syncthreads();
      } else {
        pv = shflx64(v, j);
      }
      bool up = ((t & k) == 0);
      bool small_side = ((t & j) == 0);
      bool take_min = (small_side == up);
      v = take_min ? (v < pv ? v : pv) : (v > pv ? v : pv);
    }
  }
  if (t < KK) {
    int idx = (int)(v & 0xFFFFFFFFull);
    pidx[t] = idx;
    tvs[t] = scv[idx];
    nmap[b * NPG + idx] = b * KK + t;
    out_batch[b * KK + t] = (float)b;
  }
  __syncthreads();
  for (int u2 = t; u2 < KK * 16; u2 += 1024) {
    int row = u2 >> 4, q = u2 & 15;
    int g = b * NPG + pidx[row];
    float4 vv = *(const float4*)(xl + (size_t)g * HID + q * 4);
    float tv = tvs[row];
    vv.x *= tv; vv.y *= tv; vv.z *= tv; vv.w *= tv;
    *(float4*)(out_xp + (size_t)(b * KK + row) * HID + q * 4) = vv;
  }
  __syncthreads();
  const int c = t & 63, rg = t >> 6;
  float s = 0.f, m = -INFINITY;
  for (int row = rg; row < KK; row += 16) {
    float vv = out_xp[(size_t)(b * KK + row) * HID + c];
    s += vv; m = fmaxf(m, vv);
  }
  ps[rg][c] = s; pm[rg][c] = m;
  __syncthreads();
  if (t < 64) {
    float st = 0.f, mt = -INFINITY;
#pragma unroll
    for (int g2 = 0; g2 < 16; ++g2) { st += ps[g2][t]; mt = fmaxf(mt, pm[g2][t]); }
    out_x1[b * 128 + t] = st * (1.0f / KK);
    out_x1[b * 128 + 64 + t] = mt;
  }
}

// ---------------- edge remap / filter ----------------
__global__ void edge_out_kernel(const int* __restrict__ ei, const float* __restrict__ edge,
                                const int* __restrict__ nmap,
                                float* __restrict__ out_ei, float* __restrict__ out_edge) {
  int e = blockIdx.x * 256 + threadIdx.x;
  if (e >= EE) return;
  int s = ei[e], d = ei[EE + e];
  int ns = nmap[s], nd = nmap[d];
  bool valid = (ns >= 0) && (nd >= 0);
  out_ei[e] = (float)(valid ? ns : -1);
  out_ei[EE + e] = (float)(valid ? nd : -1);
  const float4* ef = (const float4*)(edge + (size_t)e * 8);
  float4 z = make_float4(0.f, 0.f, 0.f, 0.f);
  float4 v0 = valid ? ef[0] : z;
  float4 v1 = valid ? ef[1] : z;
  float4* eo = (float4*)(out_edge + (size_t)e * 8);
  eo[0] = v0; eo[1] = v1;
}

extern "C" void kernel_launch(void* const* d_in, const int* in_sizes, int n_in,
                              void* d_out, int out_size, void* d_ws, size_t ws_size,
                              hipStream_t stream) {
  const float* x      = (const float*)d_in[0];
  const int*   ei     = (const int*)d_in[1];
  const float* edge   = (const float*)d_in[2];
  const float* W      = (const float*)d_in[4];
  const float* a_src  = (const float*)d_in[5];
  const float* a_dst  = (const float*)d_in[6];
  const float* b_gat  = (const float*)d_in[7];
  const float* W_lin  = (const float*)d_in[8];
  const float* b_lin  = (const float*)d_in[9];
  const float* p_pool = (const float*)d_in[10];

  char* ws = (char*)d_ws;
  size_t off = 0;
  auto alloc = [&](size_t bytes) -> void* {
    void* p = ws + off;
    off += (bytes + 255) & ~(size_t)255;
    return p;
  };
  float* h       = (float*)alloc((size_t)NN * CC * 4);
  float* outg    = (float*)alloc((size_t)NN * CC * 4);
  float* xl      = (float*)alloc((size_t)NN * HID * 4);
  float* al_s    = (float*)alloc((size_t)NN * NH * 4);
  float* al_d    = (float*)alloc((size_t)NN * NH * 4);
  int*   row_ptr = (int*)alloc((size_t)(NN + 1) * 4);
  int*   cnt     = (int*)alloc((size_t)NN * 4);
  int*   cnt2    = (int*)alloc((size_t)NN * 4);
  int*   col     = (int*)alloc((size_t)ETOT * 4);
  float* w4      = (float*)alloc((size_t)ETOT * NH * 4);
  int*   nmap    = (int*)alloc((size_t)NN * 4);

  float* out_xp    = (float*)d_out;
  float* out_ei    = out_xp + (size_t)BB * KK * HID;
  float* out_edge  = out_ei + 2 * (size_t)EE;
  float* out_batch = out_edge + (size_t)EE * 8;
  float* out_x1    = out_batch + (size_t)BB * KK;

  hipMemsetAsync(cnt, 0, (size_t)NN * 4, stream);

  gemm1_al_kernel<<<512, 256, 0, stream>>>(x, W, a_src, a_dst, h, al_s, al_d);
  count_kernel<<<512, 256, 0, stream>>>(ei, cnt);
  scan_g_kernel<<<BB, 1024, 0, stream>>>(cnt, row_ptr, cnt2);
  scatter_w_kernel<<<544, 256, 0, stream>>>(ei, cnt2, al_s, al_d, col, w4);
  agg_kernel<<<NN / 4, 256, 0, stream>>>(h, w4, row_ptr, col, b_gat, outg);
  gemm2_kernel<<<NN / 128, 256, 0, stream>>>(outg, W_lin, b_lin, xl);
  topk_fused_kernel<<<BB, 1024, 0, stream>>>(xl, p_pool, out_xp, nmap,
                                             out_batch, out_x1);
  edge_out_kernel<<<(EE + 255) / 256, 256, 0, stream>>>(ei, edge, nmap, out_ei, out_edge);
}

// Round 7
// 266.892 us; speedup vs baseline: 1.0581x; 1.0581x over previous
//
#include <hip/hip_runtime.h>
#include <math.h>

#define NN   32768
#define EE   524288
#define ETOT (EE + NN)
#define BB   32
#define NPG  1024
#define EPG  16384
#define RPG  17408          // CSR entries per graph = EPG + NPG (self-loops)
#define KK   512
#define INC  128
#define HID  64
#define NH   4
#define CC   256
#define SLOPE 0.2f

// ---------------- GEMM1 + al epilogue ----------------
// 128x64 tile (R5-proven occupancy: 49.4 KB LDS -> 3 blocks/CU), 4x8 micro.
// NEW vs R5: A stored TRANSPOSED in LDS (AsT[k][row], pad 129) so the 4-row
// A fragment is one ds_read_b128 (was 4x ds_read_b32): per k-iter LDS cost
// 3x b128 ~36 cyc vs 64 FMA cyc -> VALU-bound. All LDS access <=2-way (free).
// Ascending-k accumulation, identical epilogue -> h/al bit-identical to R5.
__global__ __launch_bounds__(256) void gemm1_al_kernel(const float* __restrict__ x,
                                                       const float* __restrict__ W,
                                                       const float* __restrict__ a_src,
                                                       const float* __restrict__ a_dst,
                                                       float* __restrict__ h,
                                                       float* __restrict__ al_s,
                                                       float* __restrict__ al_d) {
  __shared__ float AsT[64][129];   // [k][row], 129%32==1 -> staging writes 2-way max
  __shared__ float Bs[64][64];
  const int n0 = blockIdx.x * 128;
  const int head = blockIdx.y;
  const int c0 = head * 64;
  const int tid = threadIdx.x;
  const int rowg = tid >> 3, colg = tid & 7;   // 32 x 8 -> 4x8 micro
  const int lr = tid >> 4, lq = tid & 15;
  float acc[4][8] = {};
  for (int kc = 0; kc < 2; ++kc) {
    const int k0 = kc * 64;
#pragma unroll
    for (int p = 0; p < 8; ++p) {              // A: 128 rows x 64 k, transposed store
      int row = p * 16 + lr;
      float4 v = *(const float4*)(x + (size_t)(n0 + row) * INC + k0 + lq * 4);
      AsT[lq * 4 + 0][row] = v.x;
      AsT[lq * 4 + 1][row] = v.y;
      AsT[lq * 4 + 2][row] = v.z;
      AsT[lq * 4 + 3][row] = v.w;
    }
#pragma unroll
    for (int p = 0; p < 4; ++p) {              // B: 64 k x 64 c
      int krow = p * 16 + lr;
      *(float4*)(&Bs[krow][lq * 4]) =
          *(const float4*)(W + (size_t)(k0 + krow) * CC + c0 + lq * 4);
    }
    __syncthreads();
#pragma unroll
    for (int k = 0; k < 64; ++k) {
      float4 a = *(const float4*)(&AsT[k][rowg * 4]);   // one b128: 4 rows
      float4 b0 = *(const float4*)(&Bs[k][colg * 8]);
      float4 b1 = *(const float4*)(&Bs[k][colg * 8 + 4]);
      acc[0][0] += a.x * b0.x; acc[0][1] += a.x * b0.y; acc[0][2] += a.x * b0.z; acc[0][3] += a.x * b0.w;
      acc[0][4] += a.x * b1.x; acc[0][5] += a.x * b1.y; acc[0][6] += a.x * b1.z; acc[0][7] += a.x * b1.w;
      acc[1][0] += a.y * b0.x; acc[1][1] += a.y * b0.y; acc[1][2] += a.y * b0.z; acc[1][3] += a.y * b0.w;
      acc[1][4] += a.y * b1.x; acc[1][5] += a.y * b1.y; acc[1][6] += a.y * b1.z; acc[1][7] += a.y * b1.w;
      acc[2][0] += a.z * b0.x; acc[2][1] += a.z * b0.y; acc[2][2] += a.z * b0.z; acc[2][3] += a.z * b0.w;
      acc[2][4] += a.z * b1.x; acc[2][5] += a.z * b1.y; acc[2][6] += a.z * b1.z; acc[2][7] += a.z * b1.w;
      acc[3][0] += a.w * b0.x; acc[3][1] += a.w * b0.y; acc[3][2] += a.w * b0.z; acc[3][3] += a.w * b0.w;
      acc[3][4] += a.w * b1.x; acc[3][5] += a.w * b1.y; acc[3][6] += a.w * b1.z; acc[3][7] += a.w * b1.w;
    }
    __syncthreads();
  }
  const float4 as0 = *(const float4*)(a_src + c0 + colg * 8);
  const float4 as1 = *(const float4*)(a_src + c0 + colg * 8 + 4);
  const float4 ad0 = *(const float4*)(a_dst + c0 + colg * 8);
  const float4 ad1 = *(const float4*)(a_dst + c0 + colg * 8 + 4);
#pragma unroll
  for (int i = 0; i < 4; ++i) {
    float* hp = h + (size_t)(n0 + rowg * 4 + i) * CC + c0 + colg * 8;
    *(float4*)(hp)     = make_float4(acc[i][0], acc[i][1], acc[i][2], acc[i][3]);
    *(float4*)(hp + 4) = make_float4(acc[i][4], acc[i][5], acc[i][6], acc[i][7]);
    float ps = 0.f, pd = 0.f;
    ps += acc[i][0] * as0.x; ps += acc[i][1] * as0.y; ps += acc[i][2] * as0.z; ps += acc[i][3] * as0.w;
    ps += acc[i][4] * as1.x; ps += acc[i][5] * as1.y; ps += acc[i][6] * as1.z; ps += acc[i][7] * as1.w;
    pd += acc[i][0] * ad0.x; pd += acc[i][1] * ad0.y; pd += acc[i][2] * ad0.z; pd += acc[i][3] * ad0.w;
    pd += acc[i][4] * ad1.x; pd += acc[i][5] * ad1.y; pd += acc[i][6] * ad1.z; pd += acc[i][7] * ad1.w;
#pragma unroll
    for (int off = 4; off > 0; off >>= 1) {
      ps += __shfl_down(ps, off, 8);
      pd += __shfl_down(pd, off, 8);
    }
    if (colg == 0) {
      al_s[(n0 + rowg * 4 + i) * NH + head] = ps;
      al_d[(n0 + rowg * 4 + i) * NH + head] = pd;
    }
  }
}

// ---------------- CSR build: edge-parallel, global atomics (R5-proven) ----------------
__global__ void count_kernel(const int* __restrict__ ei, int* __restrict__ cnt) {
  int e = blockIdx.x * 256 + threadIdx.x;
  if (e >= EE) return;
  atomicAdd(&cnt[ei[EE + e]], 1);
}

__global__ __launch_bounds__(1024) void scan_g_kernel(const int* __restrict__ cnt,
                                                      int* __restrict__ row_ptr,
                                                      int* __restrict__ cnt2) {
  __shared__ int sums[NPG];
  const int b = blockIdx.x, t = threadIdx.x;
  const int c = cnt[b * NPG + t] + 1;            // + self-loop
  sums[t] = c;
  __syncthreads();
  for (int off = 1; off < NPG; off <<= 1) {
    int v = (t >= off) ? sums[t - off] : 0;
    __syncthreads();
    sums[t] += v;
    __syncthreads();
  }
  const int pos = b * RPG + sums[t] - c;
  row_ptr[b * NPG + t] = pos;
  cnt2[b * NPG + t] = pos;
  if (b == 0 && t == 0) row_ptr[NN] = ETOT;
}

__global__ void scatter_w_kernel(const int* __restrict__ ei,
                                 int* __restrict__ cnt2,
                                 const float* __restrict__ al_s,
                                 const float* __restrict__ al_d,
                                 int* __restrict__ col, float* __restrict__ w4) {
  int e = blockIdx.x * 256 + threadIdx.x;
  if (e >= ETOT) return;
  int s, d;
  if (e < EE) { s = ei[e]; d = ei[EE + e]; } else { s = e - EE; d = s; }
  int pos = atomicAdd(&cnt2[d], 1);
  col[pos] = s;
  const float4 as = *(const float4*)(al_s + s * NH);
  const float4 ad = *(const float4*)(al_d + d * NH);
  float e0 = as.x + ad.x; e0 = (e0 > 0.f) ? e0 : SLOPE * e0; float w0 = __expf(e0);
  float e1 = as.y + ad.y; e1 = (e1 > 0.f) ? e1 : SLOPE * e1; float w1 = __expf(e1);
  float e2 = as.z + ad.z; e2 = (e2 > 0.f) ? e2 : SLOPE * e2; float w2 = __expf(e2);
  float e3 = as.w + ad.w; e3 = (e3 > 0.f) ? e3 : SLOPE * e3; float w3 = __expf(e3);
  *(float4*)(w4 + (size_t)pos * 4) = make_float4(w0, w1, w2, w3);
}

// ---------------- weighted aggregation (wave per dst node; R5-proven) ----------------
__global__ __launch_bounds__(256) void agg_kernel(const float* __restrict__ h,
                                                  const float* __restrict__ w4,
                                                  const int* __restrict__ row_ptr,
                                                  const int* __restrict__ col,
                                                  const float* __restrict__ b_gat,
                                                  float* __restrict__ outg) {
  __shared__ float wsh[4][256];
  __shared__ int   csh[4][64];
  const int lane = threadIdx.x & 63;
  const int wv = threadIdx.x >> 6;
  const int hq = lane >> 4;
  const int xcd = blockIdx.x & 7;
  const int jb  = blockIdx.x >> 3;
  const int n = (xcd * 1024 + jb) * 4 + wv;
  const int beg = row_ptr[n], end = row_ptr[n + 1];
  float ax = 0.f, ay = 0.f, az = 0.f, aw = 0.f, den = 0.f;
  for (int base = beg; base < end; base += 64) {
    const int rem = end - base;
    const int cnt = rem < 64 ? rem : 64;
    if (lane < cnt) {
      csh[wv][lane] = col[base + lane];
      *(float4*)(&wsh[wv][lane * 4]) = *(const float4*)(w4 + (size_t)(base + lane) * 4);
    }
    // wave-coherent LDS region: this wave wrote before it reads
    float4 hA = *(const float4*)(h + (size_t)csh[wv][0] * CC + lane * 4);
    float4 hB = hA;
    if (cnt > 1) hB = *(const float4*)(h + (size_t)csh[wv][1] * CC + lane * 4);
    for (int i = 0; i < cnt; ++i) {
      const float w = wsh[wv][i * 4 + hq];
      float4 cur = hA;
      hA = hB;
      if (i + 2 < cnt)
        hB = *(const float4*)(h + (size_t)csh[wv][i + 2] * CC + lane * 4);
      den += w;
      ax += w * cur.x; ay += w * cur.y; az += w * cur.z; aw += w * cur.w;
    }
  }
  const float4 bg = *(const float4*)(b_gat + lane * 4);
  float4 o = make_float4(ax / den + bg.x, ay / den + bg.y,
                         az / den + bg.z, aw / den + bg.w);
  *(float4*)(outg + (size_t)n * CC + lane * 4) = o;
}

// ---------------- GEMM2 + score epilogue ----------------
// xl[N,64] = outg[N,256] @ W_lin + b_lin; score[n] = tanh(xl[n].p/||p||)
// computed in-register (width-8 shuffle over the colg lanes).
__global__ __launch_bounds__(256) void gemm2_kernel(const float* __restrict__ A,
                                                    const float* __restrict__ Wl,
                                                    const float* __restrict__ bl,
                                                    const float* __restrict__ p,
                                                    float* __restrict__ xl,
                                                    float* __restrict__ score) {
  __shared__ float As[128][65];
  __shared__ float Bs[64][64];
  const int n0 = blockIdx.x * 128;
  const int tid = threadIdx.x;
  const int rowg = tid >> 3, colg = tid & 7;
  const int lr = tid >> 4, lq = tid & 15;
  float acc[4][8] = {};
  for (int kc = 0; kc < 4; ++kc) {
    const int k0 = kc * 64;
#pragma unroll
    for (int pp = 0; pp < 8; ++pp) {
      int row = pp * 16 + lr;
      float4 v = *(const float4*)(A + (size_t)(n0 + row) * CC + k0 + lq * 4);
      As[row][lq * 4 + 0] = v.x; As[row][lq * 4 + 1] = v.y;
      As[row][lq * 4 + 2] = v.z; As[row][lq * 4 + 3] = v.w;
    }
#pragma unroll
    for (int pp = 0; pp < 4; ++pp) {
      int krow = pp * 16 + lr;
      *(float4*)(&Bs[krow][lq * 4]) =
          *(const float4*)(Wl + (size_t)(k0 + krow) * HID + lq * 4);
    }
    __syncthreads();
#pragma unroll
    for (int k = 0; k < 64; ++k) {
      float4 b0 = *(const float4*)(&Bs[k][colg * 8]);
      float4 b1 = *(const float4*)(&Bs[k][colg * 8 + 4]);
#pragma unroll
      for (int i = 0; i < 4; ++i) {
        float a = As[rowg * 4 + i][k];
        acc[i][0] += a * b0.x; acc[i][1] += a * b0.y;
        acc[i][2] += a * b0.z; acc[i][3] += a * b0.w;
        acc[i][4] += a * b1.x; acc[i][5] += a * b1.y;
        acc[i][6] += a * b1.z; acc[i][7] += a * b1.w;
      }
    }
    __syncthreads();
  }
  const float4 bv0 = *(const float4*)(bl + colg * 8);
  const float4 bv1 = *(const float4*)(bl + colg * 8 + 4);
  const float4 pv0 = *(const float4*)(p + colg * 8);
  const float4 pv1 = *(const float4*)(p + colg * 8 + 4);
  // ||p||^2 (every thread; cheap)
  float pnorm2 = 0.f;
#pragma unroll
  for (int q = 0; q < 16; ++q) {
    float4 w = *(const float4*)(p + q * 4);
    pnorm2 += w.x * w.x; pnorm2 += w.y * w.y; pnorm2 += w.z * w.z; pnorm2 += w.w * w.w;
  }
  const float rnorm = 1.0f / sqrtf(pnorm2);
#pragma unroll
  for (int i = 0; i < 4; ++i) {
    float4 v0 = make_float4(acc[i][0] + bv0.x, acc[i][1] + bv0.y,
                            acc[i][2] + bv0.z, acc[i][3] + bv0.w);
    float4 v1 = make_float4(acc[i][4] + bv1.x, acc[i][5] + bv1.y,
                            acc[i][6] + bv1.z, acc[i][7] + bv1.w);
    float* xp = xl + (size_t)(n0 + rowg * 4 + i) * HID + colg * 8;
    *(float4*)(xp)     = v0;
    *(float4*)(xp + 4) = v1;
    float dot = v0.x * pv0.x + v0.y * pv0.y + v0.z * pv0.z + v0.w * pv0.w
              + v1.x * pv1.x + v1.y * pv1.y + v1.z * pv1.z + v1.w * pv1.w;
#pragma unroll
    for (int off = 4; off > 0; off >>= 1) dot += __shfl_down(dot, off, 8);
    if (colg == 0) score[n0 + rowg * 4 + i] = tanhf(dot * rnorm);
  }
}

// ---------------- fused top-k + xp + nmap + pool (score precomputed) ----------------
__device__ inline unsigned long long shflx64(unsigned long long v, int m) {
  int lo = __shfl_xor((int)(unsigned)v, m, 64);
  int hi = __shfl_xor((int)(unsigned)(v >> 32), m, 64);
  return ((unsigned long long)(unsigned)hi << 32) | (unsigned)lo;
}

__global__ __launch_bounds__(1024) void topk_fused_kernel(const float* __restrict__ xl,
                                                          const float* __restrict__ score,
                                                          float* __restrict__ out_xp,
                                                          int* __restrict__ nmap,
                                                          float* __restrict__ out_batch,
                                                          float* __restrict__ out_x1) {
  __shared__ float scv[NPG];
  __shared__ unsigned long long keys[NPG];
  __shared__ int   pidx[KK];
  __shared__ float tvs[KK];
  __shared__ float ps[16][64];
  __shared__ float pm[16][64];
  const int b = blockIdx.x, t = threadIdx.x;
  float sc = score[b * NPG + t];
  scv[t] = sc;
  nmap[b * NPG + t] = -1;
  unsigned long long v;
  {
    unsigned u = __float_as_uint(sc);
    u = (u & 0x80000000u) ? ~u : (u | 0x80000000u);
    u = ~u;
    v = ((unsigned long long)u << 32) | (unsigned)t;
  }
  __syncthreads();
  for (int k = 2; k <= NPG; k <<= 1) {
    for (int j = k >> 1; j > 0; j >>= 1) {
      unsigned long long pv;
      if (j >= 64) {
        keys[t] = v;
        __syncthreads();
        pv = keys[t ^ j];
        __syncthreads();
      } else {
        pv = shflx64(v, j);
      }
      bool up = ((t & k) == 0);
      bool small_side = ((t & j) == 0);
      bool take_min = (small_side == up);
      v = take_min ? (v < pv ? v : pv) : (v > pv ? v : pv);
    }
  }
  if (t < KK) {
    int idx = (int)(v & 0xFFFFFFFFull);
    pidx[t] = idx;
    tvs[t] = scv[idx];
    nmap[b * NPG + idx] = b * KK + t;
    out_batch[b * KK + t] = (float)b;
  }
  __syncthreads();
  for (int u2 = t; u2 < KK * 16; u2 += 1024) {
    int row = u2 >> 4, q = u2 & 15;
    int g = b * NPG + pidx[row];
    float4 vv = *(const float4*)(xl + (size_t)g * HID + q * 4);
    float tv = tvs[row];
    vv.x *= tv; vv.y *= tv; vv.z *= tv; vv.w *= tv;
    *(float4*)(out_xp + (size_t)(b * KK + row) * HID + q * 4) = vv;
  }
  __syncthreads();
  const int c = t & 63, rg = t >> 6;
  float s = 0.f, m = -INFINITY;
  for (int row = rg; row < KK; row += 16) {
    float vv = out_xp[(size_t)(b * KK + row) * HID + c];
    s += vv; m = fmaxf(m, vv);
  }
  ps[rg][c] = s; pm[rg][c] = m;
  __syncthreads();
  if (t < 64) {
    float st = 0.f, mt = -INFINITY;
#pragma unroll
    for (int g2 = 0; g2 < 16; ++g2) { st += ps[g2][t]; mt = fmaxf(mt, pm[g2][t]); }
    out_x1[b * 128 + t] = st * (1.0f / KK);
    out_x1[b * 128 + 64 + t] = mt;
  }
}

// ---------------- edge remap / filter ----------------
__global__ void edge_out_kernel(const int* __restrict__ ei, const float* __restrict__ edge,
                                const int* __restrict__ nmap,
                                float* __restrict__ out_ei, float* __restrict__ out_edge) {
  int e = blockIdx.x * 256 + threadIdx.x;
  if (e >= EE) return;
  int s = ei[e], d = ei[EE + e];
  int ns = nmap[s], nd = nmap[d];
  bool valid = (ns >= 0) && (nd >= 0);
  out_ei[e] = (float)(valid ? ns : -1);
  out_ei[EE + e] = (float)(valid ? nd : -1);
  const float4* ef = (const float4*)(edge + (size_t)e * 8);
  float4 z = make_float4(0.f, 0.f, 0.f, 0.f);
  float4 v0 = valid ? ef[0] : z;
  float4 v1 = valid ? ef[1] : z;
  float4* eo = (float4*)(out_edge + (size_t)e * 8);
  eo[0] = v0; eo[1] = v1;
}

extern "C" void kernel_launch(void* const* d_in, const int* in_sizes, int n_in,
                              void* d_out, int out_size, void* d_ws, size_t ws_size,
                              hipStream_t stream) {
  const float* x      = (const float*)d_in[0];
  const int*   ei     = (const int*)d_in[1];
  const float* edge   = (const float*)d_in[2];
  const float* W      = (const float*)d_in[4];
  const float* a_src  = (const float*)d_in[5];
  const float* a_dst  = (const float*)d_in[6];
  const float* b_gat  = (const float*)d_in[7];
  const float* W_lin  = (const float*)d_in[8];
  const float* b_lin  = (const float*)d_in[9];
  const float* p_pool = (const float*)d_in[10];

  char* ws = (char*)d_ws;
  size_t off = 0;
  auto alloc = [&](size_t bytes) -> void* {
    void* p = ws + off;
    off += (bytes + 255) & ~(size_t)255;
    return p;
  };
  float* h       = (float*)alloc((size_t)NN * CC * 4);
  float* outg    = (float*)alloc((size_t)NN * CC * 4);
  float* xl      = (float*)alloc((size_t)NN * HID * 4);
  float* al_s    = (float*)alloc((size_t)NN * NH * 4);
  float* al_d    = (float*)alloc((size_t)NN * NH * 4);
  float* score   = (float*)alloc((size_t)NN * 4);
  int*   row_ptr = (int*)alloc((size_t)(NN + 1) * 4);
  int*   cnt     = (int*)alloc((size_t)NN * 4);
  int*   cnt2    = (int*)alloc((size_t)NN * 4);
  int*   col     = (int*)alloc((size_t)ETOT * 4);
  float* w4      = (float*)alloc((size_t)ETOT * NH * 4);
  int*   nmap    = (int*)alloc((size_t)NN * 4);

  float* out_xp    = (float*)d_out;
  float* out_ei    = out_xp + (size_t)BB * KK * HID;
  float* out_edge  = out_ei + 2 * (size_t)EE;
  float* out_batch = out_edge + (size_t)EE * 8;
  float* out_x1    = out_batch + (size_t)BB * KK;

  hipMemsetAsync(cnt, 0, (size_t)NN * 4, stream);

  gemm1_al_kernel<<<dim3(NN / 128, NH), 256, 0, stream>>>(x, W, a_src, a_dst,
                                                          h, al_s, al_d);
  count_kernel<<<EE / 256, 256, 0, stream>>>(ei, cnt);
  scan_g_kernel<<<BB, 1024, 0, stream>>>(cnt, row_ptr, cnt2);
  scatter_w_kernel<<<(ETOT + 255) / 256, 256, 0, stream>>>(ei, cnt2, al_s, al_d, col, w4);
  agg_kernel<<<NN / 4, 256, 0, stream>>>(h, w4, row_ptr, col, b_gat, outg);
  gemm2_kernel<<<NN / 128, 256, 0, stream>>>(outg, W_lin, b_lin, p_pool, xl, score);
  topk_fused_kernel<<<BB, 1024, 0, stream>>>(xl, score, out_xp, nmap,
                                             out_batch, out_x1);
  edge_out_kernel<<<(EE + 255) / 256, 256, 0, stream>>>(ei, edge, nmap, out_ei, out_edge);
}